// Round 5
// baseline (325.608 us; speedup 1.0000x reference)
//
#include <hip/hip_runtime.h>

#define THRESH 0.05f

typedef __attribute__((ext_vector_type(4))) int   int32x4;
typedef __attribute__((ext_vector_type(4))) float floatx4;

// ---------------------------------------------------------------------------
// Kernel 1: quantize weight [1024,1024] fp32 -> int8 {-1,0,+1} in FRAGMENT
// ORDER: for k-step kb (64-K chunk) and 16-col tile nb, a 1 KB block holds
// [quad][l15][16 K-bytes] so a wave's B-fragment load is lane-contiguous.
// ---------------------------------------------------------------------------
__global__ __launch_bounds__(256) void quant_w_kernel(const float* __restrict__ w,
                                                      signed char* __restrict__ wqf) {
    int c = blockIdx.x * 256 + threadIdx.x;   // 16-byte chunk id, 0..65535
    int l15  = c & 15;
    int quad = (c >> 4) & 3;
    int nb   = (c >> 6) & 63;
    int kb   = c >> 12;
    int col   = nb * 16 + l15;
    int kbase = kb * 64 + quad * 16;
    const float* src = w + col * 1024 + kbase;
    signed char q[16];
    #pragma unroll
    for (int j = 0; j < 4; ++j) {
        float4 f = *(const float4*)(src + j * 4);
        q[j * 4 + 0] = (signed char)((f.x >= THRESH) - (f.x <= -THRESH));
        q[j * 4 + 1] = (signed char)((f.y >= THRESH) - (f.y <= -THRESH));
        q[j * 4 + 2] = (signed char)((f.z >= THRESH) - (f.z <= -THRESH));
        q[j * 4 + 3] = (signed char)((f.w >= THRESH) - (f.w <= -THRESH));
    }
    *(int32x4*)(wqf + (size_t)c * 16) = *(const int32x4*)q;
}

// ---------------------------------------------------------------------------
// Kernel 2: slab-resident ternary GEMM, B software-prefetched (distance 1).
// Block = 256 threads (4 waves) x 32-row slab x all 1024 cols; 32 KB LDS,
// grid 1024 -> 4 blocks/CU, 16 waves/CU.
// Each wave: 4 col-passes of 64 cols (acc[2][4]); A-frags from LDS are
// reused across the 4 col-tiles (4x less LDS traffic than R4). B-frags
// (coalesced 1 KB loads from fragment-ordered wqf, L2-resident) are
// prefetched one k-step ahead into bf_next so the MFMAs never wait on the
// L2 round-trip. Operands swapped: D lane&15 = out row, quad*4+reg = out
// col -> float4 nt stores.
// ---------------------------------------------------------------------------
__global__ __launch_bounds__(256, 4) void tern_gemm_kernel(const float* __restrict__ x,
                                                           const signed char* __restrict__ wqf,
                                                           float* __restrict__ out) {
    __shared__ __attribute__((aligned(16))) signed char a_lds[32 * 1024];
    const int tid = threadIdx.x;
    const long rowbase = (long)blockIdx.x * 32;

    // ---- Phase 1: stage + quantize x slab (32 rows x 1024 K) ----
    #pragma unroll
    for (int i = 0; i < 8; ++i) {
        int c   = tid + i * 256;   // chunk id 0..2047
        int row = c >> 6;          // 64 chunks per row
        int cir = c & 63;          // chunk-in-row
        const floatx4* src = (const floatx4*)(x + (rowbase + row) * 1024 + cir * 16);
        signed char q[16];
        #pragma unroll
        for (int j = 0; j < 4; ++j) {
            floatx4 f = __builtin_nontemporal_load(src + j);
            #pragma unroll
            for (int e = 0; e < 4; ++e)
                q[j * 4 + e] = (signed char)((f[e] >= THRESH) - (f[e] <= -THRESH));
        }
        int swz = (cir ^ (row & 7)) * 16;  // XOR swizzle: uniform bank spread
        *(int32x4*)(a_lds + row * 1024 + swz) = *(const int32x4*)q;
    }
    __syncthreads();

    // ---- Phase 2: compute ----
    const int wave = tid >> 6;    // 0..3
    const int lane = tid & 63;
    const int l15  = lane & 15;
    const int lq   = lane >> 4;   // lane quarter
    const signed char* wq_lane = wqf + lane * 16;
    const int nb0 = wave * 16;    // wave's first 16-col tile index

    int32x4 bf_cur[4], bf_next[4];
    #pragma unroll
    for (int ci = 0; ci < 4; ++ci)   // preload (ct=0, k=0)
        bf_cur[ci] = *(const int32x4*)(wq_lane + (size_t)(nb0 + ci) * 1024);

    for (int ct = 0; ct < 4; ++ct) {
        int32x4 acc[2][4];
        #pragma unroll
        for (int ri = 0; ri < 2; ++ri)
            #pragma unroll
            for (int ci = 0; ci < 4; ++ci)
                acc[ri][ci] = (int32x4){0, 0, 0, 0};

        #pragma unroll
        for (int k = 0; k < 16; ++k) {
            // ---- prefetch B for the next (ct,k) ----
            const int nk  = (k == 15) ? 0 : k + 1;
            const int nct = (k == 15) ? ct + 1 : ct;
            if (!(ct == 3 && k == 15)) {
                #pragma unroll
                for (int ci = 0; ci < 4; ++ci)
                    bf_next[ci] = *(const int32x4*)(wq_lane +
                        (size_t)(nk * 64 + nb0 + nct * 4 + ci) * 1024);
            }

            // ---- A fragments (LDS, shared across 4 col-tiles) ----
            const int kchunk = k * 4 + lq;
            int32x4 af[2];
            #pragma unroll
            for (int ri = 0; ri < 2; ++ri) {
                int m = ri * 16 + l15;
                af[ri] = *(const int32x4*)(a_lds + m * 1024 + ((kchunk ^ (m & 7)) * 16));
            }

            // swapped operands: D lane&15 = out ROW, quad*4+reg = out COL
            #pragma unroll
            for (int ri = 0; ri < 2; ++ri)
                #pragma unroll
                for (int ci = 0; ci < 4; ++ci)
                    acc[ri][ci] = __builtin_amdgcn_mfma_i32_16x16x64_i8(
                        bf_cur[ci], af[ri], acc[ri][ci], 0, 0, 0);

            #pragma unroll
            for (int ci = 0; ci < 4; ++ci)
                bf_cur[ci] = bf_next[ci];
        }

        // ---- epilogue: lane owns 4 consecutive cols -> nt float4 stores ----
        const int cb = wave * 256 + ct * 64;
        #pragma unroll
        for (int ri = 0; ri < 2; ++ri) {
            const long row = rowbase + ri * 16 + l15;
            #pragma unroll
            for (int ci = 0; ci < 4; ++ci) {
                floatx4 v;
                v[0] = (float)acc[ri][ci][0];
                v[1] = (float)acc[ri][ci][1];
                v[2] = (float)acc[ri][ci][2];
                v[3] = (float)acc[ri][ci][3];
                __builtin_nontemporal_store(v,
                    (floatx4*)(out + row * 1024 + cb + ci * 16 + lq * 4));
            }
        }
    }
}

extern "C" void kernel_launch(void* const* d_in, const int* in_sizes, int n_in,
                              void* d_out, int out_size, void* d_ws, size_t ws_size,
                              hipStream_t stream) {
    const float* x = (const float*)d_in[0];      // [32768, 1024] fp32
    const float* w = (const float*)d_in[1];      // [1024, 1024] fp32
    float* out = (float*)d_out;                  // [32768, 1024] fp32
    signed char* wqf = (signed char*)d_ws;       // 1 MB int8 scratch (fragment order)

    quant_w_kernel<<<dim3(256), dim3(256), 0, stream>>>(w, wqf);
    // 32768 rows / 32 = 1024 blocks (4 per CU), 4 waves each
    tern_gemm_kernel<<<dim3(1024), dim3(256), 0, stream>>>(x, wqf, out);
}

// Round 6
// 298.423 us; speedup vs baseline: 1.0911x; 1.0911x over previous
//
#include <hip/hip_runtime.h>

#define THRESH 0.05f

typedef __attribute__((ext_vector_type(4))) int   int32x4;
typedef __attribute__((ext_vector_type(4))) float floatx4;

typedef __attribute__((address_space(1))) const void global_cvoid;
typedef __attribute__((address_space(3))) void lds_void;

// DMA 16 B per lane: global -> LDS (dest = wave-uniform base + lane*16)
#define GLLDS16(gp, lp) __builtin_amdgcn_global_load_lds((global_cvoid*)(gp), (lds_void*)(lp), 16, 0, 0)

// ---------------------------------------------------------------------------
// Kernel 1: quantize weight [1024,1024] fp32 -> int8 in FRAGMENT ORDER:
// 1 KB block per (k-step kb, 16-col tile nb): wqf[(kb*64+nb)*1024 + lane*16+j]
// = tern(w[nb*16 + (lane&15)][kb*64 + (lane>>4)*16 + j]).
// ---------------------------------------------------------------------------
__global__ __launch_bounds__(256) void quant_w_kernel(const float* __restrict__ w,
                                                      signed char* __restrict__ wqf) {
    int c = blockIdx.x * 256 + threadIdx.x;   // 16-byte chunk id, 0..65535
    int l15  = c & 15;
    int quad = (c >> 4) & 3;
    int nb   = (c >> 6) & 63;
    int kb   = c >> 12;
    const float* src = w + (nb * 16 + l15) * 1024 + kb * 64 + quad * 16;
    signed char q[16];
    #pragma unroll
    for (int j = 0; j < 4; ++j) {
        float4 f = *(const float4*)(src + j * 4);
        q[j * 4 + 0] = (signed char)((f.x >= THRESH) - (f.x <= -THRESH));
        q[j * 4 + 1] = (signed char)((f.y >= THRESH) - (f.y <= -THRESH));
        q[j * 4 + 2] = (signed char)((f.z >= THRESH) - (f.z <= -THRESH));
        q[j * 4 + 3] = (signed char)((f.w >= THRESH) - (f.w <= -THRESH));
    }
    *(int32x4*)(wqf + (size_t)c * 16) = *(const int32x4*)q;
}

// ---------------------------------------------------------------------------
// Kernel 2: quantize x [32768,1024] fp32 -> int8 xq, row-major with the
// per-row chunk XOR swizzle PRE-APPLIED (chunk' = chunk ^ (row&7)), so a
// linear global_load_lds DMA of a row lands in LDS already bank-spread.
// ---------------------------------------------------------------------------
__global__ __launch_bounds__(256) void quant_x_kernel(const float* __restrict__ x,
                                                      signed char* __restrict__ xq) {
    size_t c = (size_t)blockIdx.x * 256 + threadIdx.x;   // 16-float chunk id
    int row = (int)(c >> 6);
    int cir = (int)(c & 63);
    const floatx4* src = (const floatx4*)(x + c * 16);
    signed char q[16];
    #pragma unroll
    for (int j = 0; j < 4; ++j) {
        floatx4 f = __builtin_nontemporal_load(src + j);
        #pragma unroll
        for (int e = 0; e < 4; ++e)
            q[j * 4 + e] = (signed char)((f[e] >= THRESH) - (f[e] <= -THRESH));
    }
    // regular store: keep xq warm in L2/L3 for the GEMM pass
    *(int32x4*)(xq + (size_t)row * 1024 + (cir ^ (row & 7)) * 16) = *(const int32x4*)q;
}

// ---------------------------------------------------------------------------
// Kernel 3: int8 ternary GEMM, m97-style DMA K-loop.
// Block = 512 threads (8 waves) = 64 rows x 256 cols. LDS: A 64 KB (full K,
// DMA'd once) + B 16 KB (one 64-K chunk of 16 col-tiles, single-buffered).
// 80 KB -> 2 blocks/CU, 16 waves/CU. K-loop: compute chunk kc from LDS
// (pure ds_read + MFMA), barrier, DMA chunk kc+1, barrier (vmcnt drain).
// Wave = 32 rows x 64 cols (rh = wave&1, cq = wave>>1), acc[2][4].
// Operands swapped: D lane&15 = out row, quad*4+reg = out col -> float4 nt.
// ---------------------------------------------------------------------------
__global__ __launch_bounds__(512, 4) void tern_gemm_dma(const signed char* __restrict__ xq,
                                                        const signed char* __restrict__ wqf,
                                                        float* __restrict__ out) {
    __shared__ __attribute__((aligned(16))) signed char a_lds[64 * 1024];
    __shared__ __attribute__((aligned(16))) signed char b_lds[16 * 1024];

    const int tid  = threadIdx.x;
    const int wave = tid >> 6;
    const int lane = tid & 63;
    const int l15  = lane & 15;
    const int lq   = lane >> 4;
    const int rh   = wave & 1;   // row half (32 rows)
    const int cq   = wave >> 1;  // col quarter within block (64 cols)

    const int rowslab = blockIdx.x & 511;   // 64-row slab
    const int colq    = blockIdx.x >> 9;    // 256-col quarter
    const long rowbase = (long)rowslab * 64;

    // ---- preload: A (64 KB, 8 rounds) + B chunk 0 (16 KB, 2 rounds) ----
    {
        const signed char* asrc = xq + rowbase * 1024;
        #pragma unroll
        for (int r = 0; r < 8; ++r)
            GLLDS16(asrc + r * 8192 + tid * 16, a_lds + r * 8192 + wave * 1024);
        const signed char* bsrc = wqf + (size_t)(colq * 16) * 1024;
        #pragma unroll
        for (int r = 0; r < 2; ++r)
            GLLDS16(bsrc + r * 8192 + tid * 16, b_lds + r * 8192 + wave * 1024);
    }
    __syncthreads();

    int32x4 acc[2][4];
    #pragma unroll
    for (int ri = 0; ri < 2; ++ri)
        #pragma unroll
        for (int ci = 0; ci < 4; ++ci)
            acc[ri][ci] = (int32x4){0, 0, 0, 0};

    for (int kc = 0; kc < 16; ++kc) {
        // ---- compute chunk kc (LDS only) ----
        const int kchunk = kc * 4 + lq;
        int32x4 bf[4];
        #pragma unroll
        for (int ci = 0; ci < 4; ++ci)
            bf[ci] = *(const int32x4*)(b_lds + (cq * 4 + ci) * 1024 + lane * 16);
        #pragma unroll
        for (int ri = 0; ri < 2; ++ri) {
            const int m = rh * 32 + ri * 16 + l15;
            int32x4 af = *(const int32x4*)(a_lds + m * 1024 + ((kchunk ^ (m & 7)) * 16));
            #pragma unroll
            for (int ci = 0; ci < 4; ++ci)
                acc[ri][ci] = __builtin_amdgcn_mfma_i32_16x16x64_i8(
                    bf[ci], af, acc[ri][ci], 0, 0, 0);
        }

        __syncthreads();                       // all waves done reading b_lds
        if (kc < 15) {                         // DMA next B chunk
            const signed char* bsrc = wqf + (size_t)((kc + 1) * 64 + colq * 16) * 1024;
            #pragma unroll
            for (int r = 0; r < 2; ++r)
                GLLDS16(bsrc + r * 8192 + tid * 16, b_lds + r * 8192 + wave * 1024);
        }
        __syncthreads();                       // vmcnt(0) drained before barrier
    }

    // ---- epilogue ----
    #pragma unroll
    for (int ri = 0; ri < 2; ++ri) {
        const long row = rowbase + rh * 32 + ri * 16 + l15;
        #pragma unroll
        for (int ci = 0; ci < 4; ++ci) {
            floatx4 v;
            v[0] = (float)acc[ri][ci][0];
            v[1] = (float)acc[ri][ci][1];
            v[2] = (float)acc[ri][ci][2];
            v[3] = (float)acc[ri][ci][3];
            const int col = colq * 256 + cq * 64 + ci * 16 + lq * 4;
            __builtin_nontemporal_store(v, (floatx4*)(out + row * 1024 + col));
        }
    }
}

// ---------------------------------------------------------------------------
// Fallback GEMM (R4 structure) if d_ws is too small for xq. 130 us path.
// ---------------------------------------------------------------------------
__global__ __launch_bounds__(256, 4) void tern_gemm_fb(const float* __restrict__ x,
                                                       const signed char* __restrict__ wqf,
                                                       float* __restrict__ out) {
    __shared__ __attribute__((aligned(16))) signed char a_lds[32 * 1024];
    const int tid = threadIdx.x;
    const long rowbase = (long)blockIdx.x * 32;

    #pragma unroll
    for (int i = 0; i < 8; ++i) {
        int c   = tid + i * 256;
        int row = c >> 6;
        int cir = c & 63;
        const floatx4* src = (const floatx4*)(x + (rowbase + row) * 1024 + cir * 16);
        signed char q[16];
        #pragma unroll
        for (int j = 0; j < 4; ++j) {
            floatx4 f = __builtin_nontemporal_load(src + j);
            #pragma unroll
            for (int e = 0; e < 4; ++e)
                q[j * 4 + e] = (signed char)((f[e] >= THRESH) - (f[e] <= -THRESH));
        }
        *(int32x4*)(a_lds + row * 1024 + (cir ^ (row & 7)) * 16) = *(const int32x4*)q;
    }
    __syncthreads();

    const int wave = tid >> 6;
    const int lane = tid & 63;
    const int l15  = lane & 15;
    const int lq   = lane >> 4;

    for (int colit = 0; colit < 16; ++colit) {
        const int nb = colit * 4 + wave;
        int32x4 bf[16];
        #pragma unroll
        for (int k = 0; k < 16; ++k)
            bf[k] = *(const int32x4*)(wqf + (size_t)(k * 64 + nb) * 1024 + lane * 16);

        int32x4 acc[2];
        acc[0] = (int32x4){0, 0, 0, 0};
        acc[1] = (int32x4){0, 0, 0, 0};

        #pragma unroll
        for (int k = 0; k < 16; ++k) {
            const int kchunk = k * 4 + lq;
            #pragma unroll
            for (int ri = 0; ri < 2; ++ri) {
                int m = ri * 16 + l15;
                int32x4 af = *(const int32x4*)(a_lds + m * 1024 + ((kchunk ^ (m & 7)) * 16));
                acc[ri] = __builtin_amdgcn_mfma_i32_16x16x64_i8(bf[k], af, acc[ri], 0, 0, 0);
            }
        }

        const int cb = colit * 64 + wave * 16;
        #pragma unroll
        for (int ri = 0; ri < 2; ++ri) {
            const long row = rowbase + ri * 16 + l15;
            floatx4 v;
            v[0] = (float)acc[ri][0];
            v[1] = (float)acc[ri][1];
            v[2] = (float)acc[ri][2];
            v[3] = (float)acc[ri][3];
            __builtin_nontemporal_store(v, (floatx4*)(out + row * 1024 + cb + lq * 4));
        }
    }
}

extern "C" void kernel_launch(void* const* d_in, const int* in_sizes, int n_in,
                              void* d_out, int out_size, void* d_ws, size_t ws_size,
                              hipStream_t stream) {
    const float* x = (const float*)d_in[0];      // [32768, 1024] fp32
    const float* w = (const float*)d_in[1];      // [1024, 1024] fp32
    float* out = (float*)d_out;                  // [32768, 1024] fp32
    signed char* wqf = (signed char*)d_ws;       // 1 MB (fragment-ordered weight)

    quant_w_kernel<<<dim3(256), dim3(256), 0, stream>>>(w, wqf);

    const size_t need = (1u << 20) + (size_t)32768 * 1024;   // wqf + xq = 33 MB
    if (ws_size >= need) {
        signed char* xq = (signed char*)d_ws + (1u << 20);
        // 32768*1024/16 chunks / 256 = 8192 blocks
        quant_x_kernel<<<dim3(8192), dim3(256), 0, stream>>>(x, xq);
        // 512 row-slabs x 4 col-quarters = 2048 blocks (2/CU), 8 waves each
        tern_gemm_dma<<<dim3(2048), dim3(512), 0, stream>>>(xq, wqf, out);
    } else {
        tern_gemm_fb<<<dim3(1024), dim3(256), 0, stream>>>(x, wqf, out);
    }
}